// Round 3
// baseline (6229.812 us; speedup 1.0000x reference)
//
#include <hip/hip_runtime.h>
#include <math.h>

// Problem constants
#define NCOMP 20000
#define SEQT  32
#define INSZ  64
#define HSZ   128
#define EINTRA 640000
#define EINTER 4096
#define NSEC  64

#define LDH 132   // padded LDS row stride (floats) for gat_transform

__device__ __forceinline__ float dot4f(float4 a, float4 b){
  return a.x*b.x + a.y*b.y + a.z*b.z + a.w*b.w;
}
// direct FMA accumulate: 4 VALU ops per 4 MACs (dot4f+add is 5)
__device__ __forceinline__ float fma4(float4 a, float4 b, float acc){
  acc = fmaf(a.x, b.x, acc);
  acc = fmaf(a.y, b.y, acc);
  acc = fmaf(a.z, b.z, acc);
  acc = fmaf(a.w, b.w, acc);
  return acc;
}
__device__ __forceinline__ float sigm(float x){ return 1.f/(1.f + __expf(-x)); }
__device__ __forceinline__ float ftanh(float x){
  float cx = fminf(fmaxf(x, -15.f), 15.f);
  float e = __expf(2.f*cx);
  return (e - 1.f)/(e + 1.f);
}
// monotone float<->uint mapping so atomicMax works for signed floats (inter path)
__device__ __forceinline__ unsigned fordu(float f){
  unsigned b = __float_as_uint(f);
  return (b & 0x80000000u) ? ~b : (b | 0x80000000u);
}
__device__ __forceinline__ float unfordu(unsigned u){
  unsigned b = (u & 0x80000000u) ? (u & 0x7fffffffu) : ~u;
  return __uint_as_float(b);
}
#define NEG_MAX_ORD 0x00800000u   // fordu(-FLT_MAX)

// ===========================================================================
// Weight packing: Wp[k4][col] (float4 of W[col][4k4..4k4+3]), col in [0,384).
// Makes the GRU B-loads perfectly coalesced: lane l reads col l+64j -> lane
// stride 16B, 1KB/wave-instr, full cache-line utilization.
// ===========================================================================
__global__ void wpack_k(const float* __restrict__ W, float* __restrict__ Wp, int K4)
{
  int i = blockIdx.x*256 + threadIdx.x;
  if (i >= 384*K4) return;
  int k4 = i / 384, col = i - k4*384;
  int K = K4*4;
  float4 v = make_float4(W[col*K + 4*k4], W[col*K + 4*k4 + 1],
                         W[col*K + 4*k4 + 2], W[col*K + 4*k4 + 3]);
  ((float4*)Wp)[i] = v;
}

// ===========================================================================
// FUSED 2-LAYER GRU. Block = 20 companies (4 waves x 5, wave-private ->
// zero barriers in t-loop). Lane l owns output dims {l, 64+l} of all 3 gates
// (6 cols). Per k4: 5 broadcast LDS A-reads + 6 coalesced B-reads + 120 FMA.
// R=5/wave + 1000 blocks: ~3.9 blocks/CU from the grid, to hide the ~200cy
// L2 weight-load latency. launch_bounds(256,3): VGPR cap ~170 -- the (256,4)
// cap of 128 forced scratch demotion (VGPR=64, +350MB spill writes, round 1).
// Compiler should land ~100-128 VGPR -> 3-4 blocks/CU resident, NO spill.
// ===========================================================================
__global__ __launch_bounds__(256, 3)
void gru_fused(const float* __restrict__ x,
               const float* __restrict__ w0p, const float* __restrict__ u0p,
               const float* __restrict__ bih0, const float* __restrict__ bhh0,
               const float* __restrict__ w1p, const float* __restrict__ u1p,
               const float* __restrict__ bih1, const float* __restrict__ bhh1,
               float* __restrict__ seq)
{
  __shared__ float h0s[20*128];
  __shared__ float h1s[20*128];
  const int tid  = threadIdx.x;
  const int wave = tid >> 6, l = tid & 63;
  const int wrow = wave*5;
  const int c0   = blockIdx.x*20;

  float* myh0 = h0s + wrow*128;
  float* myh1 = h1s + wrow*128;
  {
    float4 z4 = make_float4(0.f,0.f,0.f,0.f);
    for (int i = l; i < 160; i += 64){     // 5 rows x 32 float4, wave-private
      ((float4*)myh0)[i] = z4;
      ((float4*)myh1)[i] = z4;
    }
  }

  // per-thread biases for cols {l, 64+l} of each gate
  const float bR0_0 = bih0[l]      + bhh0[l];
  const float bR0_1 = bih0[64+l]   + bhh0[64+l];
  const float bZ0_0 = bih0[128+l]  + bhh0[128+l];
  const float bZ0_1 = bih0[192+l]  + bhh0[192+l];
  const float bNX0_0 = bih0[256+l],  bNX0_1 = bih0[320+l];
  const float bNH0_0 = bhh0[256+l],  bNH0_1 = bhh0[320+l];
  const float bR1_0 = bih1[l]      + bhh1[l];
  const float bR1_1 = bih1[64+l]   + bhh1[64+l];
  const float bZ1_0 = bih1[128+l]  + bhh1[128+l];
  const float bZ1_1 = bih1[192+l]  + bhh1[192+l];
  const float bNX1_0 = bih1[256+l],  bNX1_1 = bih1[320+l];
  const float bNH1_0 = bhh1[256+l],  bNH1_1 = bhh1[320+l];

  const float4* x4 = (const float4*)x;
  const float4* B0 = (const float4*)w0p;   // [16][384]
  const float4* U0 = (const float4*)u0p;   // [32][384]
  const float4* B1 = (const float4*)w1p;   // [32][384]
  const float4* U1 = (const float4*)u1p;   // [32][384]
  const float4* Ah0 = (const float4*)myh0; // row m at m*32 + k4
  const float4* Ah1 = (const float4*)myh1;

  float aR[5][2], aZ[5][2], aNX[5][2], aNH[5][2];

  #pragma unroll 1
  for (int t = 0; t < SEQT; ++t){
    // ================= layer 0 =================
    #pragma unroll
    for (int m = 0; m < 5; ++m){
      aR[m][0]=bR0_0; aR[m][1]=bR0_1; aZ[m][0]=bZ0_0; aZ[m][1]=bZ0_1;
      aNX[m][0]=bNX0_0; aNX[m][1]=bNX0_1; aNH[m][0]=bNH0_0; aNH[m][1]=bNH0_1;
    }
    // x part, K=64 (A broadcast from global, likely s_load)
    const float4* Ax = x4 + (size_t)(c0+wrow)*512 + t*16;  // row m at +m*512
    #pragma unroll 2
    for (int k4 = 0; k4 < 16; ++k4){
      float4 b0 = B0[k4*384 + l];
      float4 b1 = B0[k4*384 + 64 + l];
      float4 b2 = B0[k4*384 + 128 + l];
      float4 b3 = B0[k4*384 + 192 + l];
      float4 b4 = B0[k4*384 + 256 + l];
      float4 b5 = B0[k4*384 + 320 + l];
      #pragma unroll
      for (int m = 0; m < 5; ++m){
        float4 a = Ax[m*512 + k4];
        aR[m][0]  = fma4(a, b0, aR[m][0]);  aR[m][1]  = fma4(a, b1, aR[m][1]);
        aZ[m][0]  = fma4(a, b2, aZ[m][0]);  aZ[m][1]  = fma4(a, b3, aZ[m][1]);
        aNX[m][0] = fma4(a, b4, aNX[m][0]); aNX[m][1] = fma4(a, b5, aNX[m][1]);
      }
    }
    // h part, K=128 (A broadcast from LDS)
    #pragma unroll 2
    for (int k4 = 0; k4 < 32; ++k4){
      float4 b0 = U0[k4*384 + l];
      float4 b1 = U0[k4*384 + 64 + l];
      float4 b2 = U0[k4*384 + 128 + l];
      float4 b3 = U0[k4*384 + 192 + l];
      float4 b4 = U0[k4*384 + 256 + l];
      float4 b5 = U0[k4*384 + 320 + l];
      #pragma unroll
      for (int m = 0; m < 5; ++m){
        float4 a = Ah0[m*32 + k4];
        aR[m][0]  = fma4(a, b0, aR[m][0]);  aR[m][1]  = fma4(a, b1, aR[m][1]);
        aZ[m][0]  = fma4(a, b2, aZ[m][0]);  aZ[m][1]  = fma4(a, b3, aZ[m][1]);
        aNH[m][0] = fma4(a, b4, aNH[m][0]); aNH[m][1] = fma4(a, b5, aNH[m][1]);
      }
    }
    // elementwise -> update h0 (dims l, 64+l per company)
    #pragma unroll
    for (int m = 0; m < 5; ++m){
      float ho0 = myh0[m*128 + l], ho1 = myh0[m*128 + 64 + l];
      float r0 = sigm(aR[m][0]), z0 = sigm(aZ[m][0]);
      float n0 = ftanh(aNX[m][0] + r0*aNH[m][0]);
      float r1 = sigm(aR[m][1]), z1 = sigm(aZ[m][1]);
      float n1 = ftanh(aNX[m][1] + r1*aNH[m][1]);
      myh0[m*128 + l]      = (1.f - z0)*n0 + z0*ho0;
      myh0[m*128 + 64 + l] = (1.f - z1)*n1 + z1*ho1;
    }

    // ================= layer 1 =================
    #pragma unroll
    for (int m = 0; m < 5; ++m){
      aR[m][0]=bR1_0; aR[m][1]=bR1_1; aZ[m][0]=bZ1_0; aZ[m][1]=bZ1_1;
      aNX[m][0]=bNX1_0; aNX[m][1]=bNX1_1; aNH[m][0]=bNH1_0; aNH[m][1]=bNH1_1;
    }
    // input = new h0, K=128
    #pragma unroll 2
    for (int k4 = 0; k4 < 32; ++k4){
      float4 b0 = B1[k4*384 + l];
      float4 b1 = B1[k4*384 + 64 + l];
      float4 b2 = B1[k4*384 + 128 + l];
      float4 b3 = B1[k4*384 + 192 + l];
      float4 b4 = B1[k4*384 + 256 + l];
      float4 b5 = B1[k4*384 + 320 + l];
      #pragma unroll
      for (int m = 0; m < 5; ++m){
        float4 a = Ah0[m*32 + k4];
        aR[m][0]  = fma4(a, b0, aR[m][0]);  aR[m][1]  = fma4(a, b1, aR[m][1]);
        aZ[m][0]  = fma4(a, b2, aZ[m][0]);  aZ[m][1]  = fma4(a, b3, aZ[m][1]);
        aNX[m][0] = fma4(a, b4, aNX[m][0]); aNX[m][1] = fma4(a, b5, aNX[m][1]);
      }
    }
    // hidden h1, K=128
    #pragma unroll 2
    for (int k4 = 0; k4 < 32; ++k4){
      float4 b0 = U1[k4*384 + l];
      float4 b1 = U1[k4*384 + 64 + l];
      float4 b2 = U1[k4*384 + 128 + l];
      float4 b3 = U1[k4*384 + 192 + l];
      float4 b4 = U1[k4*384 + 256 + l];
      float4 b5 = U1[k4*384 + 320 + l];
      #pragma unroll
      for (int m = 0; m < 5; ++m){
        float4 a = Ah1[m*32 + k4];
        aR[m][0]  = fma4(a, b0, aR[m][0]);  aR[m][1]  = fma4(a, b1, aR[m][1]);
        aZ[m][0]  = fma4(a, b2, aZ[m][0]);  aZ[m][1]  = fma4(a, b3, aZ[m][1]);
        aNH[m][0] = fma4(a, b4, aNH[m][0]); aNH[m][1] = fma4(a, b5, aNH[m][1]);
      }
    }
    #pragma unroll
    for (int m = 0; m < 5; ++m){
      float ho0 = myh1[m*128 + l], ho1 = myh1[m*128 + 64 + l];
      float r0 = sigm(aR[m][0]), z0 = sigm(aZ[m][0]);
      float n0 = ftanh(aNX[m][0] + r0*aNH[m][0]);
      float r1 = sigm(aR[m][1]), z1 = sigm(aZ[m][1]);
      float n1 = ftanh(aNX[m][1] + r1*aNH[m][1]);
      float hn0 = (1.f - z0)*n0 + z0*ho0;
      float hn1 = (1.f - z1)*n1 + z1*ho1;
      myh1[m*128 + l]      = hn0;
      myh1[m*128 + 64 + l] = hn1;
      if (t == SEQT-1){
        seq[(size_t)(c0 + wrow + m)*128 + l]      = hn0;
        seq[(size_t)(c0 + wrow + m)*128 + 64 + l] = hn1;
      }
    }
  }
}

// ===========================================================================
// GAT stage — CSR build + atomic-free per-node gather
// ===========================================================================
__global__ __launch_bounds__(256)
void gat_transform(const float* __restrict__ X, const float* __restrict__ W,
                   const float* __restrict__ asrc, const float* __restrict__ adst,
                   float* __restrict__ Hout, float* __restrict__ es, float* __restrict__ ed,
                   int n)
{
  __shared__ float sX[64*LDH];
  const int tid = threadIdx.x;
  const long base = (long)blockIdx.x * 64;
  for (int i = tid; i < 64*32; i += 256){
    int row = i >> 5, q = i & 31;
    long gr = base + row;
    float4 v = make_float4(0.f, 0.f, 0.f, 0.f);
    if (gr < n) v = ((const float4*)(X + gr*HSZ))[q];
    ((float4*)(sX + row*LDH))[q] = v;
  }
  __syncthreads();
  const int rp = tid >> 3, dg = tid & 7;
  const int r0 = rp*2, r1 = r0 + 1;
  const float4* xa = (const float4*)(sX + r0*LDH);
  const float4* xb = (const float4*)(sX + r1*LDH);
  float ps0=0.f, pd0=0.f, ps1=0.f, pd1=0.f;
  for (int dd = 0; dd < 16; ++dd){
    const int cidx = dg*16 + dd;
    const float4* wp = (const float4*)(W + cidx*HSZ);
    float a0 = 0.f, a1 = 0.f;
    #pragma unroll 4
    for (int q = 0; q < 32; ++q){
      float4 w = wp[q];
      a0 += dot4f(w, xa[q]);
      a1 += dot4f(w, xb[q]);
    }
    float s = asrc[cidx], dv = adst[cidx];
    ps0 += a0*s; pd0 += a0*dv;
    ps1 += a1*s; pd1 += a1*dv;
    if (base + r0 < n) Hout[(base+r0)*HSZ + cidx] = a0;
    if (base + r1 < n) Hout[(base+r1)*HSZ + cidx] = a1;
  }
  #pragma unroll
  for (int m = 1; m < 8; m <<= 1){
    ps0 += __shfl_xor(ps0, m, 64);
    pd0 += __shfl_xor(pd0, m, 64);
    ps1 += __shfl_xor(ps1, m, 64);
    pd1 += __shfl_xor(pd1, m, 64);
  }
  if (dg == 0){
    if (base + r0 < n){ es[base+r0] = ps0; ed[base+r0] = pd0; }
    if (base + r1 < n){ es[base+r1] = ps1; ed[base+r1] = pd1; }
  }
}

__global__ void zero_i(int* __restrict__ p, int n)
{
  int i = blockIdx.x*256 + threadIdx.x;
  if (i < n) p[i] = 0;
}

__global__ void csr_count(const int* __restrict__ key, int* __restrict__ cnt, int E)
{
  int i = blockIdx.x*256 + threadIdx.x;
  if (i < E) atomicAdd(&cnt[key[i]], 1);
}

// single block, 1024 threads: exclusive scan of cnt[0..n) -> rowptr, cursor
__global__ __launch_bounds__(1024)
void csr_scan(const int* __restrict__ cnt, int* __restrict__ rowptr,
              int* __restrict__ cursor, int n)
{
  __shared__ int ls[1024];
  const int t = threadIdx.x;
  const int base = t*20;
  int loc[20];
  int s = 0;
  #pragma unroll
  for (int k = 0; k < 20; ++k){
    int idx = base + k;
    int v = (idx < n) ? cnt[idx] : 0;
    loc[k] = s; s += v;
  }
  ls[t] = s;
  __syncthreads();
  for (int off = 1; off < 1024; off <<= 1){
    int v = (t >= off) ? ls[t-off] : 0;
    __syncthreads();
    ls[t] += v;
    __syncthreads();
  }
  int excl = (t == 0) ? 0 : ls[t-1];
  #pragma unroll
  for (int k = 0; k < 20; ++k){
    int idx = base + k;
    if (idx < n){ int rp = excl + loc[k]; rowptr[idx] = rp; cursor[idx] = rp; }
  }
  if (t == 1023) rowptr[n] = ls[1023];
}

// val==nullptr -> store the element index i (used for sector row lists)
__global__ void csr_fill(const int* __restrict__ val, const int* __restrict__ key,
                         int* __restrict__ cursor, int* __restrict__ outl, int E)
{
  int i = blockIdx.x*256 + threadIdx.x;
  if (i >= E) return;
  int p = atomicAdd(&cursor[key[i]], 1);
  outl[p] = val ? val[i] : i;
}

// one wave per destination node: leaky-relu logits, max, denom, weighted gather
__global__ __launch_bounds__(256)
void gat_gather(const int* __restrict__ rowptr, const int* __restrict__ csrc,
                const float* __restrict__ es, const float* __restrict__ ed,
                const float* __restrict__ Hv, const float* __restrict__ bias,
                float* __restrict__ out, int n)
{
  int d = blockIdx.x*4 + (threadIdx.x >> 6);
  int l = threadIdx.x & 63;
  if (d >= n) return;
  const int p0 = rowptr[d], p1 = rowptr[d+1];
  const float edd = ed[d];
  float eself = es[d] + edd;
  eself = eself > 0.f ? eself : 0.2f*eself;
  float m = eself;
  for (int j = p0 + l; j < p1; j += 64){
    int s = csrc[j];
    float e = es[s] + edd;
    e = e > 0.f ? e : 0.2f*e;
    m = fmaxf(m, e);
  }
  #pragma unroll
  for (int off = 1; off < 64; off <<= 1) m = fmaxf(m, __shfl_xor(m, off, 64));
  float part = 0.f;
  for (int j = p0 + l; j < p1; j += 64){
    int s = csrc[j];
    float e = es[s] + edd;
    e = e > 0.f ? e : 0.2f*e;
    part += __expf(e - m);
  }
  #pragma unroll
  for (int off = 1; off < 64; off <<= 1) part += __shfl_xor(part, off, 64);
  const float wself = __expf(eself - m);
  const float inv = 1.f/(part + wself);
  float a = wself*inv;
  float acc0 = a * Hv[(long)d*HSZ + l];
  float acc1 = a * Hv[(long)d*HSZ + 64 + l];
  for (int j = p0; j < p1; ++j){
    int s = csrc[j];
    float e = es[s] + edd;
    e = e > 0.f ? e : 0.2f*e;
    float al = __expf(e - m)*inv;
    acc0 += al * Hv[(long)s*HSZ + l];
    acc1 += al * Hv[(long)s*HSZ + 64 + l];
  }
  out[(long)d*HSZ + l]      = acc0 + bias[l];
  out[(long)d*HSZ + 64 + l] = acc1 + bias[64 + l];
}

// per-sector max pool using sector row-list (CSR over sid)
__global__ __launch_bounds__(256)
void sector_pool(const float* __restrict__ intra, const int* __restrict__ srowptr,
                 const int* __restrict__ slist, float* __restrict__ spool)
{
  const int sec = blockIdx.x;
  const int t = threadIdx.x;
  const int d = t & 127, half = t >> 7;
  const int p0 = srowptr[sec], p1 = srowptr[sec+1];
  float m = -3.402823466e+38f;
  for (int j = p0 + half; j < p1; j += 2){
    int r = slist[j];
    m = fmaxf(m, intra[(long)r*HSZ + d]);
  }
  __shared__ float red[256];
  red[t] = m;
  __syncthreads();
  if (half == 0) spool[sec*HSZ + d] = fmaxf(red[d], red[128 + d]);
}

// ---- inter-sector GAT (tiny, keep atomic path) ----
__global__ void gat_init(unsigned* __restrict__ maxb, float* __restrict__ den,
                         float* __restrict__ acc, int n)
{
  long i = (long)blockIdx.x*256 + threadIdx.x;
  if (i < n){ maxb[i] = NEG_MAX_ORD; den[i] = 0.f; }
  if (i < (long)n*HSZ) acc[i] = 0.f;
}

__global__ void edge_max(const int* __restrict__ src, const int* __restrict__ dst,
                         const float* __restrict__ es, const float* __restrict__ ed,
                         unsigned* __restrict__ maxb, int E, int n)
{
  int i = blockIdx.x*256 + threadIdx.x;
  if (i >= E + n) return;
  int s, d;
  if (i < E){ s = src[i]; d = dst[i]; } else { s = d = i - E; }
  float e = es[s] + ed[d];
  e = e > 0.f ? e : 0.2f*e;
  atomicMax(maxb + d, fordu(e));
}

__global__ void edge_sum(const int* __restrict__ src, const int* __restrict__ dst,
                         const float* __restrict__ es, const float* __restrict__ ed,
                         const unsigned* __restrict__ maxb, float* __restrict__ den,
                         float* __restrict__ wbuf, int E, int n)
{
  int i = blockIdx.x*256 + threadIdx.x;
  if (i >= E + n) return;
  int s, d;
  if (i < E){ s = src[i]; d = dst[i]; } else { s = d = i - E; }
  float e = es[s] + ed[d];
  e = e > 0.f ? e : 0.2f*e;
  float w = __expf(e - unfordu(maxb[d]));
  wbuf[i] = w;
  atomicAdd(den + d, w);
}

__global__ void edge_scatter(const int* __restrict__ src, const int* __restrict__ dst,
                             const float* __restrict__ wbuf, const float* __restrict__ den,
                             const float* __restrict__ Hv, float* __restrict__ acc,
                             int E, int n)
{
  long t = (long)blockIdx.x*256 + threadIdx.x;
  long i = t >> 5;
  int  j = (int)(t & 31);
  if (i >= E + n) return;
  int s, d;
  if (i < E){ s = src[i]; d = dst[i]; } else { s = d = (int)(i - E); }
  float alpha = wbuf[i] / den[d];
  float4 hv = ((const float4*)(Hv + (long)s*HSZ))[j];
  float* o = acc + (long)d*HSZ + j*4;
  atomicAdd(o+0, alpha*hv.x);
  atomicAdd(o+1, alpha*hv.y);
  atomicAdd(o+2, alpha*hv.z);
  atomicAdd(o+3, alpha*hv.w);
}

__global__ void inter_bias_k(const float* __restrict__ acc2, const float* __restrict__ bias,
                             float* __restrict__ isec)
{
  int i = blockIdx.x*256 + threadIdx.x;   // exactly 64*128
  isec[i] = acc2[i] + bias[i & 127];
}

__global__ __launch_bounds__(256)
void fusion_k(const float* __restrict__ seq, const float* __restrict__ intra,
              const float* __restrict__ isec, const int* __restrict__ sid,
              const float* __restrict__ fw, const float* __restrict__ fb,
              float* __restrict__ out, int n)
{
  int i = blockIdx.x*4 + (threadIdx.x >> 6);
  int l = threadIdx.x & 63;
  if (i >= n) return;
  int sc = sid[i];
  long b = (long)i*HSZ;
  long sb = (long)sc*HSZ;
  float acc = fw[l]     * seq[b + l]      + fw[64 + l]  * seq[b + 64 + l]
            + fw[128+l] * intra[b + l]    + fw[192 + l] * intra[b + 64 + l]
            + fw[256+l] * isec[sb + l]    + fw[320 + l] * isec[sb + 64 + l];
  #pragma unroll
  for (int m = 1; m < 64; m <<= 1) acc += __shfl_xor(acc, m, 64);
  if (l == 0) out[i] = acc + fb[0];
}

extern "C" void kernel_launch(void* const* d_in, const int* in_sizes, int n_in,
                              void* d_out, int out_size, void* d_ws, size_t ws_size,
                              hipStream_t stream)
{
  const float* x    = (const float*)d_in[0];
  const int*   iei  = (const int*)d_in[1];    // [2, 640000]
  const int*   eei  = (const int*)d_in[2];    // [2, 4096]
  const int*   sid  = (const int*)d_in[3];
  const float* wih0 = (const float*)d_in[4];
  const float* whh0 = (const float*)d_in[5];
  const float* bih0 = (const float*)d_in[6];
  const float* bhh0 = (const float*)d_in[7];
  const float* wih1 = (const float*)d_in[8];
  const float* whh1 = (const float*)d_in[9];
  const float* bih1 = (const float*)d_in[10];
  const float* bhh1 = (const float*)d_in[11];
  const float* iW   = (const float*)d_in[12];
  const float* ias  = (const float*)d_in[13];
  const float* iad  = (const float*)d_in[14];
  const float* ib   = (const float*)d_in[15];
  const float* eW   = (const float*)d_in[16];
  const float* eas  = (const float*)d_in[17];
  const float* ead  = (const float*)d_in[18];
  const float* eb   = (const float*)d_in[19];
  const float* fW   = (const float*)d_in[20];
  const float* fb   = (const float*)d_in[21];

  float* ws = (float*)d_ws;
  long off = 0;
  float* seq    = ws + off; off += 2560000;
  float* hintra = ws + off; off += 2560000;
  float* intra  = ws + off; off += 2560000;
  float* es     = ws + off; off += 20000;
  float* ed     = ws + off; off += 20000;
  int*   cnt    = (int*)(ws + off); off += 20000;
  int*   rowptr = (int*)(ws + off); off += 20004;
  int*   cursor = (int*)(ws + off); off += 20000;
  int*   csrc   = (int*)(ws + off); off += 640000;
  int*   scnt    = (int*)(ws + off); off += 64;
  int*   srowptr = (int*)(ws + off); off += 68;
  int*   scursor = (int*)(ws + off); off += 64;
  int*   slist   = (int*)(ws + off); off += 20000;
  float* w0p = ws + off; off += 24576;   // 384 x 64 packed
  float* u0p = ws + off; off += 49152;   // 384 x 128
  float* w1p = ws + off; off += 49152;
  float* u1p = ws + off; off += 49152;
  float* spool  = ws + off; off += 8192;
  float* hinter = ws + off; off += 8192;
  float* acc2   = ws + off; off += 8192;
  float* es2    = ws + off; off += 64;
  float* ed2    = ws + off; off += 64;
  unsigned* mx2 = (unsigned*)(ws + off); off += 64;
  float* den2   = ws + off; off += 64;
  float* wbf2   = ws + off; off += 4160;
  float* isec   = ws + off; off += 8192;
  // total ~8.6M floats = ~34.5 MB

  // 0) pack GRU weights k-major (tiny)
  wpack_k<<<24, 256, 0, stream>>>(wih0, w0p, 16);
  wpack_k<<<48, 256, 0, stream>>>(whh0, u0p, 32);
  wpack_k<<<48, 256, 0, stream>>>(wih1, w1p, 32);
  wpack_k<<<48, 256, 0, stream>>>(whh1, u1p, 32);

  // 1) fused 2-layer GRU -> seq_emb  (one dispatch, 20 companies/block)
  gru_fused<<<1000, 256, 0, stream>>>(x, w0p, u0p, bih0, bhh0,
                                      w1p, u1p, bih1, bhh1, seq);

  // 2) intra GAT: transform + CSR build + atomic-free gather
  gat_transform<<<313, 256, 0, stream>>>(seq, iW, ias, iad, hintra, es, ed, NCOMP);
  zero_i   <<<(NCOMP+255)/256, 256, 0, stream>>>(cnt, NCOMP);
  zero_i   <<<1, 256, 0, stream>>>(scnt, NSEC);
  csr_count<<<(EINTRA+255)/256, 256, 0, stream>>>(iei + EINTRA, cnt, EINTRA);
  csr_count<<<(NCOMP+255)/256, 256, 0, stream>>>(sid, scnt, NCOMP);
  csr_scan <<<1, 1024, 0, stream>>>(cnt, rowptr, cursor, NCOMP);
  csr_scan <<<1, 1024, 0, stream>>>(scnt, srowptr, scursor, NSEC);
  csr_fill <<<(EINTRA+255)/256, 256, 0, stream>>>(iei, iei + EINTRA, cursor, csrc, EINTRA);
  csr_fill <<<(NCOMP+255)/256, 256, 0, stream>>>(nullptr, sid, scursor, slist, NCOMP);
  gat_gather<<<NCOMP/4, 256, 0, stream>>>(rowptr, csrc, es, ed, hintra, ib, intra, NCOMP);

  // 3) per-sector max pool via sector row lists
  sector_pool<<<NSEC, 256, 0, stream>>>(intra, srowptr, slist, spool);

  // 4) inter GAT (tiny: 64 nodes, 4096 edges — atomic path)
  gat_init<<<32, 256, 0, stream>>>(mx2, den2, acc2, NSEC);
  gat_transform<<<1, 256, 0, stream>>>(spool, eW, eas, ead, hinter, es2, ed2, NSEC);
  {
    int tot = EINTER + NSEC;
    edge_max    <<<(tot+255)/256, 256, 0, stream>>>(eei, eei+EINTER, es2, ed2, mx2, EINTER, NSEC);
    edge_sum    <<<(tot+255)/256, 256, 0, stream>>>(eei, eei+EINTER, es2, ed2, mx2, den2, wbf2, EINTER, NSEC);
    edge_scatter<<<(tot*32)/256, 256, 0, stream>>>(eei, eei+EINTER, wbf2, den2, hinter, acc2, EINTER, NSEC);
  }
  inter_bias_k<<<32, 256, 0, stream>>>(acc2, eb, isec);

  // 5) fusion -> output [20000]
  fusion_k<<<NCOMP/4, 256, 0, stream>>>(seq, intra, isec, sid, fW, fb, (float*)d_out, NCOMP);
}

// Round 4
// 4529.150 us; speedup vs baseline: 1.3755x; 1.3755x over previous
//
#include <hip/hip_runtime.h>
#include <math.h>

// Problem constants
#define NCOMP 20000
#define SEQT  32
#define INSZ  64
#define HSZ   128
#define EINTRA 640000
#define EINTER 4096
#define NSEC  64

#define LDH 132   // padded LDS row stride (floats) for gat_transform

__device__ __forceinline__ float dot4f(float4 a, float4 b){
  return a.x*b.x + a.y*b.y + a.z*b.z + a.w*b.w;
}
// direct FMA accumulate: 4 VALU ops per 4 MACs (dot4f+add is 5).
// Validated numerically in round 3 (absmax unchanged at 4.88e-4).
__device__ __forceinline__ float fma4(float4 a, float4 b, float acc){
  acc = fmaf(a.x, b.x, acc);
  acc = fmaf(a.y, b.y, acc);
  acc = fmaf(a.z, b.z, acc);
  acc = fmaf(a.w, b.w, acc);
  return acc;
}
__device__ __forceinline__ float sigm(float x){ return 1.f/(1.f + __expf(-x)); }
__device__ __forceinline__ float ftanh(float x){
  float cx = fminf(fmaxf(x, -15.f), 15.f);
  float e = __expf(2.f*cx);
  return (e - 1.f)/(e + 1.f);
}
// monotone float<->uint mapping so atomicMax works for signed floats (inter path)
__device__ __forceinline__ unsigned fordu(float f){
  unsigned b = __float_as_uint(f);
  return (b & 0x80000000u) ? ~b : (b | 0x80000000u);
}
__device__ __forceinline__ float unfordu(unsigned u){
  unsigned b = (u & 0x80000000u) ? (u & 0x7fffffffu) : ~u;
  return __uint_as_float(b);
}
#define NEG_MAX_ORD 0x00800000u   // fordu(-FLT_MAX)

// ===========================================================================
// Weight packing: Wp[k4][col] (float4 of W[col][4k4..4k4+3]), col in [0,384).
// Makes the GRU B-loads perfectly coalesced: lane l reads col l+64j -> lane
// stride 16B, 1KB/wave-instr, full cache-line utilization.
// ===========================================================================
__global__ void wpack_k(const float* __restrict__ W, float* __restrict__ Wp, int K4)
{
  int i = blockIdx.x*256 + threadIdx.x;
  if (i >= 384*K4) return;
  int k4 = i / 384, col = i - k4*384;
  int K = K4*4;
  float4 v = make_float4(W[col*K + 4*k4], W[col*K + 4*k4 + 1],
                         W[col*K + 4*k4 + 2], W[col*K + 4*k4 + 3]);
  ((float4*)Wp)[i] = v;
}

// ===========================================================================
// FUSED 2-LAYER GRU. Block = 40 companies (4 waves x 10, wave-private ->
// zero barriers in t-loop). Lane l owns output dims {l, 64+l} of all 3 gates
// (6 cols). Per k4: 10 broadcast LDS A-reads + 6 coalesced B-reads + 240 FMA.
// CONFIG NOTE (rounds 1-3 evidence): R=10 / 500 blocks / (256,2) is the
// proven schedule (VGPR=120, deep load pipelining, VALU 60%). Shrinking R to
// 5 with tighter launch_bounds made the compiler pick a 72-VGPR schedule
// that serialized B-loads (VALU 44%, dur +17%). Registers > occupancy here.
// ===========================================================================
__global__ __launch_bounds__(256, 2)
void gru_fused(const float* __restrict__ x,
               const float* __restrict__ w0p, const float* __restrict__ u0p,
               const float* __restrict__ bih0, const float* __restrict__ bhh0,
               const float* __restrict__ w1p, const float* __restrict__ u1p,
               const float* __restrict__ bih1, const float* __restrict__ bhh1,
               float* __restrict__ seq)
{
  __shared__ float h0s[40*128];
  __shared__ float h1s[40*128];
  const int tid  = threadIdx.x;
  const int wave = tid >> 6, l = tid & 63;
  const int wrow = wave*10;
  const int c0   = blockIdx.x*40;

  float* myh0 = h0s + wrow*128;
  float* myh1 = h1s + wrow*128;
  {
    float4 z4 = make_float4(0.f,0.f,0.f,0.f);
    for (int i = l; i < 320; i += 64){     // 10 rows x 32 float4, wave-private
      ((float4*)myh0)[i] = z4;
      ((float4*)myh1)[i] = z4;
    }
  }

  // per-thread biases for cols {l, 64+l} of each gate
  const float bR0_0 = bih0[l]      + bhh0[l];
  const float bR0_1 = bih0[64+l]   + bhh0[64+l];
  const float bZ0_0 = bih0[128+l]  + bhh0[128+l];
  const float bZ0_1 = bih0[192+l]  + bhh0[192+l];
  const float bNX0_0 = bih0[256+l],  bNX0_1 = bih0[320+l];
  const float bNH0_0 = bhh0[256+l],  bNH0_1 = bhh0[320+l];
  const float bR1_0 = bih1[l]      + bhh1[l];
  const float bR1_1 = bih1[64+l]   + bhh1[64+l];
  const float bZ1_0 = bih1[128+l]  + bhh1[128+l];
  const float bZ1_1 = bih1[192+l]  + bhh1[192+l];
  const float bNX1_0 = bih1[256+l],  bNX1_1 = bih1[320+l];
  const float bNH1_0 = bhh1[256+l],  bNH1_1 = bhh1[320+l];

  const float4* x4 = (const float4*)x;
  const float4* B0 = (const float4*)w0p;   // [16][384]
  const float4* U0 = (const float4*)u0p;   // [32][384]
  const float4* B1 = (const float4*)w1p;   // [32][384]
  const float4* U1 = (const float4*)u1p;   // [32][384]
  const float4* Ah0 = (const float4*)myh0; // row m at m*32 + k4
  const float4* Ah1 = (const float4*)myh1;

  float aR[10][2], aZ[10][2], aNX[10][2], aNH[10][2];

  #pragma unroll 1
  for (int t = 0; t < SEQT; ++t){
    // ================= layer 0 =================
    #pragma unroll
    for (int m = 0; m < 10; ++m){
      aR[m][0]=bR0_0; aR[m][1]=bR0_1; aZ[m][0]=bZ0_0; aZ[m][1]=bZ0_1;
      aNX[m][0]=bNX0_0; aNX[m][1]=bNX0_1; aNH[m][0]=bNH0_0; aNH[m][1]=bNH0_1;
    }
    // x part, K=64 (A broadcast from global, lane-invariant -> s_load)
    const float4* Ax = x4 + (size_t)(c0+wrow)*512 + t*16;  // row m at +m*512
    #pragma unroll 2
    for (int k4 = 0; k4 < 16; ++k4){
      float4 b0 = B0[k4*384 + l];
      float4 b1 = B0[k4*384 + 64 + l];
      float4 b2 = B0[k4*384 + 128 + l];
      float4 b3 = B0[k4*384 + 192 + l];
      float4 b4 = B0[k4*384 + 256 + l];
      float4 b5 = B0[k4*384 + 320 + l];
      #pragma unroll
      for (int m = 0; m < 10; ++m){
        float4 a = Ax[m*512 + k4];
        aR[m][0]  = fma4(a, b0, aR[m][0]);  aR[m][1]  = fma4(a, b1, aR[m][1]);
        aZ[m][0]  = fma4(a, b2, aZ[m][0]);  aZ[m][1]  = fma4(a, b3, aZ[m][1]);
        aNX[m][0] = fma4(a, b4, aNX[m][0]); aNX[m][1] = fma4(a, b5, aNX[m][1]);
      }
    }
    // h part, K=128 (A broadcast from LDS)
    #pragma unroll 2
    for (int k4 = 0; k4 < 32; ++k4){
      float4 b0 = U0[k4*384 + l];
      float4 b1 = U0[k4*384 + 64 + l];
      float4 b2 = U0[k4*384 + 128 + l];
      float4 b3 = U0[k4*384 + 192 + l];
      float4 b4 = U0[k4*384 + 256 + l];
      float4 b5 = U0[k4*384 + 320 + l];
      #pragma unroll
      for (int m = 0; m < 10; ++m){
        float4 a = Ah0[m*32 + k4];
        aR[m][0]  = fma4(a, b0, aR[m][0]);  aR[m][1]  = fma4(a, b1, aR[m][1]);
        aZ[m][0]  = fma4(a, b2, aZ[m][0]);  aZ[m][1]  = fma4(a, b3, aZ[m][1]);
        aNH[m][0] = fma4(a, b4, aNH[m][0]); aNH[m][1] = fma4(a, b5, aNH[m][1]);
      }
    }
    // elementwise -> update h0 (dims l, 64+l per company)
    #pragma unroll
    for (int m = 0; m < 10; ++m){
      float ho0 = myh0[m*128 + l], ho1 = myh0[m*128 + 64 + l];
      float r0 = sigm(aR[m][0]), z0 = sigm(aZ[m][0]);
      float n0 = ftanh(aNX[m][0] + r0*aNH[m][0]);
      float r1 = sigm(aR[m][1]), z1 = sigm(aZ[m][1]);
      float n1 = ftanh(aNX[m][1] + r1*aNH[m][1]);
      myh0[m*128 + l]      = (1.f - z0)*n0 + z0*ho0;
      myh0[m*128 + 64 + l] = (1.f - z1)*n1 + z1*ho1;
    }

    // ================= layer 1 =================
    #pragma unroll
    for (int m = 0; m < 10; ++m){
      aR[m][0]=bR1_0; aR[m][1]=bR1_1; aZ[m][0]=bZ1_0; aZ[m][1]=bZ1_1;
      aNX[m][0]=bNX1_0; aNX[m][1]=bNX1_1; aNH[m][0]=bNH1_0; aNH[m][1]=bNH1_1;
    }
    // input = new h0, K=128
    #pragma unroll 2
    for (int k4 = 0; k4 < 32; ++k4){
      float4 b0 = B1[k4*384 + l];
      float4 b1 = B1[k4*384 + 64 + l];
      float4 b2 = B1[k4*384 + 128 + l];
      float4 b3 = B1[k4*384 + 192 + l];
      float4 b4 = B1[k4*384 + 256 + l];
      float4 b5 = B1[k4*384 + 320 + l];
      #pragma unroll
      for (int m = 0; m < 10; ++m){
        float4 a = Ah0[m*32 + k4];
        aR[m][0]  = fma4(a, b0, aR[m][0]);  aR[m][1]  = fma4(a, b1, aR[m][1]);
        aZ[m][0]  = fma4(a, b2, aZ[m][0]);  aZ[m][1]  = fma4(a, b3, aZ[m][1]);
        aNX[m][0] = fma4(a, b4, aNX[m][0]); aNX[m][1] = fma4(a, b5, aNX[m][1]);
      }
    }
    // hidden h1, K=128
    #pragma unroll 2
    for (int k4 = 0; k4 < 32; ++k4){
      float4 b0 = U1[k4*384 + l];
      float4 b1 = U1[k4*384 + 64 + l];
      float4 b2 = U1[k4*384 + 128 + l];
      float4 b3 = U1[k4*384 + 192 + l];
      float4 b4 = U1[k4*384 + 256 + l];
      float4 b5 = U1[k4*384 + 320 + l];
      #pragma unroll
      for (int m = 0; m < 10; ++m){
        float4 a = Ah1[m*32 + k4];
        aR[m][0]  = fma4(a, b0, aR[m][0]);  aR[m][1]  = fma4(a, b1, aR[m][1]);
        aZ[m][0]  = fma4(a, b2, aZ[m][0]);  aZ[m][1]  = fma4(a, b3, aZ[m][1]);
        aNH[m][0] = fma4(a, b4, aNH[m][0]); aNH[m][1] = fma4(a, b5, aNH[m][1]);
      }
    }
    #pragma unroll
    for (int m = 0; m < 10; ++m){
      float ho0 = myh1[m*128 + l], ho1 = myh1[m*128 + 64 + l];
      float r0 = sigm(aR[m][0]), z0 = sigm(aZ[m][0]);
      float n0 = ftanh(aNX[m][0] + r0*aNH[m][0]);
      float r1 = sigm(aR[m][1]), z1 = sigm(aZ[m][1]);
      float n1 = ftanh(aNX[m][1] + r1*aNH[m][1]);
      float hn0 = (1.f - z0)*n0 + z0*ho0;
      float hn1 = (1.f - z1)*n1 + z1*ho1;
      myh1[m*128 + l]      = hn0;
      myh1[m*128 + 64 + l] = hn1;
      if (t == SEQT-1){
        seq[(size_t)(c0 + wrow + m)*128 + l]      = hn0;
        seq[(size_t)(c0 + wrow + m)*128 + 64 + l] = hn1;
      }
    }
  }
}

// ===========================================================================
// GAT stage — CSR build + atomic-free per-node gather
// ===========================================================================
__global__ __launch_bounds__(256)
void gat_transform(const float* __restrict__ X, const float* __restrict__ W,
                   const float* __restrict__ asrc, const float* __restrict__ adst,
                   float* __restrict__ Hout, float* __restrict__ es, float* __restrict__ ed,
                   int n)
{
  __shared__ float sX[64*LDH];
  const int tid = threadIdx.x;
  const long base = (long)blockIdx.x * 64;
  for (int i = tid; i < 64*32; i += 256){
    int row = i >> 5, q = i & 31;
    long gr = base + row;
    float4 v = make_float4(0.f, 0.f, 0.f, 0.f);
    if (gr < n) v = ((const float4*)(X + gr*HSZ))[q];
    ((float4*)(sX + row*LDH))[q] = v;
  }
  __syncthreads();
  const int rp = tid >> 3, dg = tid & 7;
  const int r0 = rp*2, r1 = r0 + 1;
  const float4* xa = (const float4*)(sX + r0*LDH);
  const float4* xb = (const float4*)(sX + r1*LDH);
  float ps0=0.f, pd0=0.f, ps1=0.f, pd1=0.f;
  for (int dd = 0; dd < 16; ++dd){
    const int cidx = dg*16 + dd;
    const float4* wp = (const float4*)(W + cidx*HSZ);
    float a0 = 0.f, a1 = 0.f;
    #pragma unroll 4
    for (int q = 0; q < 32; ++q){
      float4 w = wp[q];
      a0 += dot4f(w, xa[q]);
      a1 += dot4f(w, xb[q]);
    }
    float s = asrc[cidx], dv = adst[cidx];
    ps0 += a0*s; pd0 += a0*dv;
    ps1 += a1*s; pd1 += a1*dv;
    if (base + r0 < n) Hout[(base+r0)*HSZ + cidx] = a0;
    if (base + r1 < n) Hout[(base+r1)*HSZ + cidx] = a1;
  }
  #pragma unroll
  for (int m = 1; m < 8; m <<= 1){
    ps0 += __shfl_xor(ps0, m, 64);
    pd0 += __shfl_xor(pd0, m, 64);
    ps1 += __shfl_xor(ps1, m, 64);
    pd1 += __shfl_xor(pd1, m, 64);
  }
  if (dg == 0){
    if (base + r0 < n){ es[base+r0] = ps0; ed[base+r0] = pd0; }
    if (base + r1 < n){ es[base+r1] = ps1; ed[base+r1] = pd1; }
  }
}

__global__ void zero_i(int* __restrict__ p, int n)
{
  int i = blockIdx.x*256 + threadIdx.x;
  if (i < n) p[i] = 0;
}

__global__ void csr_count(const int* __restrict__ key, int* __restrict__ cnt, int E)
{
  int i = blockIdx.x*256 + threadIdx.x;
  if (i < E) atomicAdd(&cnt[key[i]], 1);
}

// single block, 1024 threads: exclusive scan of cnt[0..n) -> rowptr, cursor
__global__ __launch_bounds__(1024)
void csr_scan(const int* __restrict__ cnt, int* __restrict__ rowptr,
              int* __restrict__ cursor, int n)
{
  __shared__ int ls[1024];
  const int t = threadIdx.x;
  const int base = t*20;
  int loc[20];
  int s = 0;
  #pragma unroll
  for (int k = 0; k < 20; ++k){
    int idx = base + k;
    int v = (idx < n) ? cnt[idx] : 0;
    loc[k] = s; s += v;
  }
  ls[t] = s;
  __syncthreads();
  for (int off = 1; off < 1024; off <<= 1){
    int v = (t >= off) ? ls[t-off] : 0;
    __syncthreads();
    ls[t] += v;
    __syncthreads();
  }
  int excl = (t == 0) ? 0 : ls[t-1];
  #pragma unroll
  for (int k = 0; k < 20; ++k){
    int idx = base + k;
    if (idx < n){ int rp = excl + loc[k]; rowptr[idx] = rp; cursor[idx] = rp; }
  }
  if (t == 1023) rowptr[n] = ls[1023];
}

// val==nullptr -> store the element index i (used for sector row lists)
__global__ void csr_fill(const int* __restrict__ val, const int* __restrict__ key,
                         int* __restrict__ cursor, int* __restrict__ outl, int E)
{
  int i = blockIdx.x*256 + threadIdx.x;
  if (i >= E) return;
  int p = atomicAdd(&cursor[key[i]], 1);
  outl[p] = val ? val[i] : i;
}

// one wave per destination node: leaky-relu logits, max, denom, weighted gather
__global__ __launch_bounds__(256)
void gat_gather(const int* __restrict__ rowptr, const int* __restrict__ csrc,
                const float* __restrict__ es, const float* __restrict__ ed,
                const float* __restrict__ Hv, const float* __restrict__ bias,
                float* __restrict__ out, int n)
{
  int d = blockIdx.x*4 + (threadIdx.x >> 6);
  int l = threadIdx.x & 63;
  if (d >= n) return;
  const int p0 = rowptr[d], p1 = rowptr[d+1];
  const float edd = ed[d];
  float eself = es[d] + edd;
  eself = eself > 0.f ? eself : 0.2f*eself;
  float m = eself;
  for (int j = p0 + l; j < p1; j += 64){
    int s = csrc[j];
    float e = es[s] + edd;
    e = e > 0.f ? e : 0.2f*e;
    m = fmaxf(m, e);
  }
  #pragma unroll
  for (int off = 1; off < 64; off <<= 1) m = fmaxf(m, __shfl_xor(m, off, 64));
  float part = 0.f;
  for (int j = p0 + l; j < p1; j += 64){
    int s = csrc[j];
    float e = es[s] + edd;
    e = e > 0.f ? e : 0.2f*e;
    part += __expf(e - m);
  }
  #pragma unroll
  for (int off = 1; off < 64; off <<= 1) part += __shfl_xor(part, off, 64);
  const float wself = __expf(eself - m);
  const float inv = 1.f/(part + wself);
  float a = wself*inv;
  float acc0 = a * Hv[(long)d*HSZ + l];
  float acc1 = a * Hv[(long)d*HSZ + 64 + l];
  for (int j = p0; j < p1; ++j){
    int s = csrc[j];
    float e = es[s] + edd;
    e = e > 0.f ? e : 0.2f*e;
    float al = __expf(e - m)*inv;
    acc0 += al * Hv[(long)s*HSZ + l];
    acc1 += al * Hv[(long)s*HSZ + 64 + l];
  }
  out[(long)d*HSZ + l]      = acc0 + bias[l];
  out[(long)d*HSZ + 64 + l] = acc1 + bias[64 + l];
}

// per-sector max pool using sector row-list (CSR over sid)
__global__ __launch_bounds__(256)
void sector_pool(const float* __restrict__ intra, const int* __restrict__ srowptr,
                 const int* __restrict__ slist, float* __restrict__ spool)
{
  const int sec = blockIdx.x;
  const int t = threadIdx.x;
  const int d = t & 127, half = t >> 7;
  const int p0 = srowptr[sec], p1 = srowptr[sec+1];
  float m = -3.402823466e+38f;
  for (int j = p0 + half; j < p1; j += 2){
    int r = slist[j];
    m = fmaxf(m, intra[(long)r*HSZ + d]);
  }
  __shared__ float red[256];
  red[t] = m;
  __syncthreads();
  if (half == 0) spool[sec*HSZ + d] = fmaxf(red[d], red[128 + d]);
}

// ---- inter-sector GAT (tiny, keep atomic path) ----
__global__ void gat_init(unsigned* __restrict__ maxb, float* __restrict__ den,
                         float* __restrict__ acc, int n)
{
  long i = (long)blockIdx.x*256 + threadIdx.x;
  if (i < n){ maxb[i] = NEG_MAX_ORD; den[i] = 0.f; }
  if (i < (long)n*HSZ) acc[i] = 0.f;
}

__global__ void edge_max(const int* __restrict__ src, const int* __restrict__ dst,
                         const float* __restrict__ es, const float* __restrict__ ed,
                         unsigned* __restrict__ maxb, int E, int n)
{
  int i = blockIdx.x*256 + threadIdx.x;
  if (i >= E + n) return;
  int s, d;
  if (i < E){ s = src[i]; d = dst[i]; } else { s = d = i - E; }
  float e = es[s] + ed[d];
  e = e > 0.f ? e : 0.2f*e;
  atomicMax(maxb + d, fordu(e));
}

__global__ void edge_sum(const int* __restrict__ src, const int* __restrict__ dst,
                         const float* __restrict__ es, const float* __restrict__ ed,
                         const unsigned* __restrict__ maxb, float* __restrict__ den,
                         float* __restrict__ wbuf, int E, int n)
{
  int i = blockIdx.x*256 + threadIdx.x;
  if (i >= E + n) return;
  int s, d;
  if (i < E){ s = src[i]; d = dst[i]; } else { s = d = i - E; }
  float e = es[s] + ed[d];
  e = e > 0.f ? e : 0.2f*e;
  float w = __expf(e - unfordu(maxb[d]));
  wbuf[i] = w;
  atomicAdd(den + d, w);
}

__global__ void edge_scatter(const int* __restrict__ src, const int* __restrict__ dst,
                             const float* __restrict__ wbuf, const float* __restrict__ den,
                             const float* __restrict__ Hv, float* __restrict__ acc,
                             int E, int n)
{
  long t = (long)blockIdx.x*256 + threadIdx.x;
  long i = t >> 5;
  int  j = (int)(t & 31);
  if (i >= E + n) return;
  int s, d;
  if (i < E){ s = src[i]; d = dst[i]; } else { s = d = (int)(i - E); }
  float alpha = wbuf[i] / den[d];
  float4 hv = ((const float4*)(Hv + (long)s*HSZ))[j];
  float* o = acc + (long)d*HSZ + j*4;
  atomicAdd(o+0, alpha*hv.x);
  atomicAdd(o+1, alpha*hv.y);
  atomicAdd(o+2, alpha*hv.z);
  atomicAdd(o+3, alpha*hv.w);
}

__global__ void inter_bias_k(const float* __restrict__ acc2, const float* __restrict__ bias,
                             float* __restrict__ isec)
{
  int i = blockIdx.x*256 + threadIdx.x;   // exactly 64*128
  isec[i] = acc2[i] + bias[i & 127];
}

__global__ __launch_bounds__(256)
void fusion_k(const float* __restrict__ seq, const float* __restrict__ intra,
              const float* __restrict__ isec, const int* __restrict__ sid,
              const float* __restrict__ fw, const float* __restrict__ fb,
              float* __restrict__ out, int n)
{
  int i = blockIdx.x*4 + (threadIdx.x >> 6);
  int l = threadIdx.x & 63;
  if (i >= n) return;
  int sc = sid[i];
  long b = (long)i*HSZ;
  long sb = (long)sc*HSZ;
  float acc = fw[l]     * seq[b + l]      + fw[64 + l]  * seq[b + 64 + l]
            + fw[128+l] * intra[b + l]    + fw[192 + l] * intra[b + 64 + l]
            + fw[256+l] * isec[sb + l]    + fw[320 + l] * isec[sb + 64 + l];
  #pragma unroll
  for (int m = 1; m < 64; m <<= 1) acc += __shfl_xor(acc, m, 64);
  if (l == 0) out[i] = acc + fb[0];
}

extern "C" void kernel_launch(void* const* d_in, const int* in_sizes, int n_in,
                              void* d_out, int out_size, void* d_ws, size_t ws_size,
                              hipStream_t stream)
{
  const float* x    = (const float*)d_in[0];
  const int*   iei  = (const int*)d_in[1];    // [2, 640000]
  const int*   eei  = (const int*)d_in[2];    // [2, 4096]
  const int*   sid  = (const int*)d_in[3];
  const float* wih0 = (const float*)d_in[4];
  const float* whh0 = (const float*)d_in[5];
  const float* bih0 = (const float*)d_in[6];
  const float* bhh0 = (const float*)d_in[7];
  const float* wih1 = (const float*)d_in[8];
  const float* whh1 = (const float*)d_in[9];
  const float* bih1 = (const float*)d_in[10];
  const float* bhh1 = (const float*)d_in[11];
  const float* iW   = (const float*)d_in[12];
  const float* ias  = (const float*)d_in[13];
  const float* iad  = (const float*)d_in[14];
  const float* ib   = (const float*)d_in[15];
  const float* eW   = (const float*)d_in[16];
  const float* eas  = (const float*)d_in[17];
  const float* ead  = (const float*)d_in[18];
  const float* eb   = (const float*)d_in[19];
  const float* fW   = (const float*)d_in[20];
  const float* fb   = (const float*)d_in[21];

  float* ws = (float*)d_ws;
  long off = 0;
  float* seq    = ws + off; off += 2560000;
  float* hintra = ws + off; off += 2560000;
  float* intra  = ws + off; off += 2560000;
  float* es     = ws + off; off += 20000;
  float* ed     = ws + off; off += 20000;
  int*   cnt    = (int*)(ws + off); off += 20000;
  int*   rowptr = (int*)(ws + off); off += 20004;
  int*   cursor = (int*)(ws + off); off += 20000;
  int*   csrc   = (int*)(ws + off); off += 640000;
  int*   scnt    = (int*)(ws + off); off += 64;
  int*   srowptr = (int*)(ws + off); off += 68;
  int*   scursor = (int*)(ws + off); off += 64;
  int*   slist   = (int*)(ws + off); off += 20000;
  float* w0p = ws + off; off += 24576;   // 384 x 64 packed
  float* u0p = ws + off; off += 49152;   // 384 x 128
  float* w1p = ws + off; off += 49152;
  float* u1p = ws + off; off += 49152;
  float* spool  = ws + off; off += 8192;
  float* hinter = ws + off; off += 8192;
  float* acc2   = ws + off; off += 8192;
  float* es2    = ws + off; off += 64;
  float* ed2    = ws + off; off += 64;
  unsigned* mx2 = (unsigned*)(ws + off); off += 64;
  float* den2   = ws + off; off += 64;
  float* wbf2   = ws + off; off += 4160;
  float* isec   = ws + off; off += 8192;
  // total ~8.6M floats = ~34.5 MB

  // 0) pack GRU weights k-major (tiny)
  wpack_k<<<24, 256, 0, stream>>>(wih0, w0p, 16);
  wpack_k<<<48, 256, 0, stream>>>(whh0, u0p, 32);
  wpack_k<<<48, 256, 0, stream>>>(wih1, w1p, 32);
  wpack_k<<<48, 256, 0, stream>>>(whh1, u1p, 32);

  // 1) fused 2-layer GRU -> seq_emb  (one dispatch)
  gru_fused<<<500, 256, 0, stream>>>(x, w0p, u0p, bih0, bhh0,
                                     w1p, u1p, bih1, bhh1, seq);

  // 2) intra GAT: transform + CSR build + atomic-free gather
  gat_transform<<<313, 256, 0, stream>>>(seq, iW, ias, iad, hintra, es, ed, NCOMP);
  zero_i   <<<(NCOMP+255)/256, 256, 0, stream>>>(cnt, NCOMP);
  zero_i   <<<1, 256, 0, stream>>>(scnt, NSEC);
  csr_count<<<(EINTRA+255)/256, 256, 0, stream>>>(iei + EINTRA, cnt, EINTRA);
  csr_count<<<(NCOMP+255)/256, 256, 0, stream>>>(sid, scnt, NCOMP);
  csr_scan <<<1, 1024, 0, stream>>>(cnt, rowptr, cursor, NCOMP);
  csr_scan <<<1, 1024, 0, stream>>>(scnt, srowptr, scursor, NSEC);
  csr_fill <<<(EINTRA+255)/256, 256, 0, stream>>>(iei, iei + EINTRA, cursor, csrc, EINTRA);
  csr_fill <<<(NCOMP+255)/256, 256, 0, stream>>>(nullptr, sid, scursor, slist, NCOMP);
  gat_gather<<<NCOMP/4, 256, 0, stream>>>(rowptr, csrc, es, ed, hintra, ib, intra, NCOMP);

  // 3) per-sector max pool via sector row lists
  sector_pool<<<NSEC, 256, 0, stream>>>(intra, srowptr, slist, spool);

  // 4) inter GAT (tiny: 64 nodes, 4096 edges — atomic path)
  gat_init<<<32, 256, 0, stream>>>(mx2, den2, acc2, NSEC);
  gat_transform<<<1, 256, 0, stream>>>(spool, eW, eas, ead, hinter, es2, ed2, NSEC);
  {
    int tot = EINTER + NSEC;
    edge_max    <<<(tot+255)/256, 256, 0, stream>>>(eei, eei+EINTER, es2, ed2, mx2, EINTER, NSEC);
    edge_sum    <<<(tot+255)/256, 256, 0, stream>>>(eei, eei+EINTER, es2, ed2, mx2, den2, wbf2, EINTER, NSEC);
    edge_scatter<<<(tot*32)/256, 256, 0, stream>>>(eei, eei+EINTER, wbf2, den2, hinter, acc2, EINTER, NSEC);
  }
  inter_bias_k<<<32, 256, 0, stream>>>(acc2, eb, isec);

  // 5) fusion -> output [20000]
  fusion_k<<<NCOMP/4, 256, 0, stream>>>(seq, intra, isec, sid, fW, fb, (float*)d_out, NCOMP);
}